// Round 1
// baseline (332.465 us; speedup 1.0000x reference)
//
#include <hip/hip_runtime.h>
#include <hip/hip_bf16.h>
#include <math.h>

// Problem constants
#define B    8
#define C4   64
#define CQ   16
#define NN   512
#define L4   12
#define FCN  (L4*CQ)      // 192 floats of Fc per (b,n)
#define XLEN (C4*L4)      // 768 floats of x per (b,n)
#define NCHUNK 16         // n's per pass-2 block
#define NCH  (NN/NCHUNK)  // 32 chunks
#define KT   128          // k-tile in final kernel

// workspace layout (float offsets)
#define O_XT   0                            // x transposed [B][N][C4][L4]   3145728
#define O_FCT  (O_XT + (size_t)B*NN*XLEN)   // Fc^T [B][N][L4][CQ]            786432
#define O_XX   (O_FCT + (size_t)B*NN*FCN)   // [B][CQ] sum Fl^2                  128
#define O_YY   (O_XX + B*CQ)                // [B][CQ] sum Fc^2                  128
#define O_L2   (O_YY + B*CQ)                // [B] 1/l2 (+pad)                    16
#define O_AMAX (O_L2 + 16)                  // A[b][n][k]                    2097152
#define O_WARR (O_AMAX + (size_t)B*NN*NN)   // A^T: W[b][n][k]=A[b][k][n]    2097152
#define O_PART (O_WARR + (size_t)B*NN*NN)   // xg partials [B][NCH][C4][N]   8388608

// K1: Fc = W_conv x + b_conv (transposed store), x transpose, norm partials.
__global__ __launch_bounds__(256) void k1_fc(const float* __restrict__ x,
                                             const float* __restrict__ Wc,
                                             const float* __restrict__ bc,
                                             float* __restrict__ ws) {
  int blk = blockIdx.x;             // b*512 + n
  int b = blk >> 9;
  int n = blk & 511;
  int t = threadIdx.x;
  __shared__ __align__(16) float xs[XLEN];
  __shared__ float wcs[C4*CQ];      // [c][q]
  __shared__ float bcs[CQ];
  __shared__ float red[FCN];

  for (int e = t; e < C4*CQ; e += 256) {   // W transposed into LDS
    int c = e >> 4, q = e & 15;
    wcs[e] = Wc[q*C4 + c];
  }
  if (t < CQ) bcs[t] = bc[t];
  const float* xb = x + (size_t)b*C4*NN*L4 + (size_t)n*L4;
  for (int e = t; e < XLEN; e += 256) {
    int c = e / L4, j = e - c*L4;
    xs[e] = xb[(size_t)c*NN*L4 + j];
  }
  __syncthreads();
  float* xt = ws + O_XT + (size_t)blk*XLEN;
  for (int e = t; e < XLEN; e += 256) xt[e] = xs[e];

  if (t < FCN) {
    int q = t & 15, j = t >> 4;
    float acc = bcs[q];
    #pragma unroll
    for (int c = 0; c < C4; ++c) acc += wcs[c*CQ + q] * xs[c*L4 + j];
    ws[O_FCT + (size_t)blk*FCN + t] = acc;
    red[t] = acc*acc;
  }
  __syncthreads();
  if (t < CQ) {
    float yy = 0.f;
    #pragma unroll
    for (int j = 0; j < L4; ++j) yy += red[j*CQ + t];
    float xx = red[(L4-1)*CQ + t];
    atomicAdd(ws + O_YY + b*CQ + t, yy);
    atomicAdd(ws + O_XX + b*CQ + t, xx);
  }
}

// K1b: l2inv[b] = 1 / sum_q sqrt(xx)*sqrt(yy)
__global__ void k1b_l2(float* __restrict__ ws) {
  int t = threadIdx.x;              // 128 threads = B*CQ
  __shared__ float s[B*CQ];
  s[t] = sqrtf(ws[O_XX + t]) * sqrtf(ws[O_YY + t]);
  __syncthreads();
  if (t < B) {
    float sum = 0.f;
    #pragma unroll
    for (int q = 0; q < CQ; ++q) sum += s[t*CQ + q];
    ws[O_L2 + t] = 1.0f / sum;
  }
}

// K2 (pass 1): per (b,n), A[b][n][k] = relu(tanh(max_c R[b,c,n,k]))
__global__ __launch_bounds__(256) void k2_amax(float* __restrict__ ws) {
  int blk = blockIdx.x;             // b*512 + n
  int b = blk >> 9;
  int t = threadIdx.x;
  __shared__ __align__(16) float fcn[FCN];
  __shared__ __align__(16) float xs[XLEN];
  const float* fct = ws + O_FCT;
  if (t < FCN) fcn[t] = fct[(size_t)blk*FCN + t];
  const float* xt = ws + O_XT + (size_t)blk*XLEN;
  for (int e = t; e < XLEN; e += 256) xs[e] = xt[e];
  float l2inv = ws[O_L2 + b];
  int k0 = t, k1 = t + 256;
  float fl0[CQ], fl1[CQ];
  const float* flbase = fct + (size_t)b*NN*FCN + (L4-1)*CQ;
  #pragma unroll
  for (int q = 0; q < CQ; ++q) {
    fl0[q] = flbase[(size_t)k0*FCN + q];
    fl1[q] = flbase[(size_t)k1*FCN + q];
  }
  __syncthreads();
  float sn0[L4], sn1[L4];
  #pragma unroll
  for (int j = 0; j < L4; ++j) {
    float a0 = 0.f, a1 = 0.f;
    #pragma unroll
    for (int q = 0; q < CQ; ++q) { float f = fcn[j*CQ + q]; a0 += fl0[q]*f; a1 += fl1[q]*f; }
    sn0[j] = a0 * l2inv; sn1[j] = a1 * l2inv;
  }
  float m0 = -INFINITY, m1 = -INFINITY;
  for (int c = 0; c < C4; ++c) {
    const float* xc = &xs[c*L4];
    float d0 = 0.f, d1 = 0.f;
    #pragma unroll
    for (int j = 0; j < L4; ++j) { float xv = xc[j]; d0 += xv*sn0[j]; d1 += xv*sn1[j]; }
    m0 = fmaxf(m0, d0); m1 = fmaxf(m1, d1);
  }
  float* am = ws + O_AMAX + (size_t)blk*NN;
  am[k0] = fmaxf(tanhf(m0), 0.f);
  am[k1] = fmaxf(tanhf(m1), 0.f);
}

// K2b: W[b][n][k] = A[b][k][n] (per-batch transpose, 32x32 tiles)
__global__ __launch_bounds__(256) void k2b_tr(float* __restrict__ ws) {
  int blk = blockIdx.x;             // b*256 + bi*16 + bj
  int b  = blk >> 8;
  int bi = (blk >> 4) & 15;
  int bj = blk & 15;
  int t = threadIdx.x;
  int tx = t & 31, ty = t >> 5;     // 32 x 8
  __shared__ float tile[32][33];
  const float* am = ws + O_AMAX + (size_t)b*NN*NN;
  float* wa = ws + O_WARR + (size_t)b*NN*NN;
  #pragma unroll
  for (int i = 0; i < 4; ++i) {
    int row = ty + i*8;
    tile[row][tx] = am[(size_t)(bi*32+row)*NN + bj*32 + tx];
  }
  __syncthreads();
  #pragma unroll
  for (int i = 0; i < 4; ++i) {
    int row = ty + i*8;
    wa[(size_t)(bj*32+row)*NN + bi*32 + tx] = tile[tx][row];
  }
}

// K3 (pass 2): split-K partials of xg[b,c,k] = sum_n R[b,c,n,k]*A[b,k,n]
__global__ __launch_bounds__(256, 2) void k3_xg(float* __restrict__ ws) {
  int blk = blockIdx.x;             // b*NCH + ch
  int b = blk / NCH, ch = blk % NCH;
  int t = threadIdx.x;
  __shared__ __align__(16) float fcn[FCN];
  __shared__ __align__(16) float xs[XLEN];
  float l2inv = ws[O_L2 + b];
  int k0 = t, k1 = t + 256;
  float fl0[CQ], fl1[CQ];
  const float* flbase = ws + O_FCT + (size_t)b*NN*FCN + (L4-1)*CQ;
  #pragma unroll
  for (int q = 0; q < CQ; ++q) {
    fl0[q] = flbase[(size_t)k0*FCN + q];
    fl1[q] = flbase[(size_t)k1*FCN + q];
  }
  float acc0[C4], acc1[C4];
  #pragma unroll
  for (int c = 0; c < C4; ++c) { acc0[c] = 0.f; acc1[c] = 0.f; }

  for (int ni = 0; ni < NCHUNK; ++ni) {
    size_t bn = (size_t)b*NN + (ch*NCHUNK + ni);
    __syncthreads();
    if (t < FCN) fcn[t] = ws[O_FCT + bn*FCN + t];
    for (int e = t; e < XLEN; e += 256) xs[e] = ws[O_XT + bn*XLEN + e];
    __syncthreads();
    float w0 = ws[O_WARR + bn*NN + k0] * l2inv;   // fold 1/l2 into weight
    float w1 = ws[O_WARR + bn*NN + k1] * l2inv;
    float sn0[L4], sn1[L4];
    #pragma unroll
    for (int j = 0; j < L4; ++j) {
      float a0 = 0.f, a1 = 0.f;
      #pragma unroll
      for (int q = 0; q < CQ; ++q) { float f = fcn[j*CQ + q]; a0 += fl0[q]*f; a1 += fl1[q]*f; }
      sn0[j] = a0; sn1[j] = a1;
    }
    for (int c = 0; c < C4; ++c) {
      const float* xc = &xs[c*L4];
      float d0 = 0.f, d1 = 0.f;
      #pragma unroll
      for (int j = 0; j < L4; ++j) { float xv = xc[j]; d0 += xv*sn0[j]; d1 += xv*sn1[j]; }
      acc0[c] += w0*d0; acc1[c] += w1*d1;
    }
  }
  float* part = ws + O_PART + (size_t)blk*C4*NN;
  for (int c = 0; c < C4; ++c) {
    part[(size_t)c*NN + k0] = acc0[c];
    part[(size_t)c*NN + k1] = acc1[c];
  }
}

// K4: reduce partials -> xg, then Fg = W_gcn xg + b_gcn
__global__ __launch_bounds__(256) void k4_out(const float* __restrict__ Wg,
                                              const float* __restrict__ bg,
                                              const float* __restrict__ ws,
                                              float* __restrict__ out) {
  int blk = blockIdx.x;             // b*4 + kc
  int b = blk >> 2, kc = blk & 3;
  int t = threadIdx.x;
  __shared__ float xg[C4][KT+1];
  __shared__ float wg[C4*C4];
  for (int e = t; e < C4*C4; e += 256) wg[e] = Wg[e];
  const float* part = ws + O_PART + (size_t)b*NCH*C4*NN;
  for (int e = t; e < C4*KT; e += 256) {
    int c = e >> 7, kk = e & (KT-1);
    float s = 0.f;
    for (int chn = 0; chn < NCH; ++chn)
      s += part[((size_t)chn*C4 + c)*NN + kc*KT + kk];
    xg[c][kk] = s;
  }
  __syncthreads();
  int kk = t & (KT-1);
  int ohalf = t >> 7;
  for (int oi = 0; oi < 32; ++oi) {
    int o = ohalf*32 + oi;
    float acc = bg[o];
    #pragma unroll
    for (int c = 0; c < C4; ++c) acc += wg[o*C4 + c] * xg[c][kk];
    out[((size_t)(b*C4 + o))*NN + kc*KT + kk] = acc;
  }
}

extern "C" void kernel_launch(void* const* d_in, const int* in_sizes, int n_in,
                              void* d_out, int out_size, void* d_ws, size_t ws_size,
                              hipStream_t stream) {
  const float* x  = (const float*)d_in[0];
  const float* Wc = (const float*)d_in[1];
  const float* bc = (const float*)d_in[2];
  const float* Wg = (const float*)d_in[3];
  const float* bg = (const float*)d_in[4];
  float* ws  = (float*)d_ws;
  float* out = (float*)d_out;

  // zero the norm accumulators (ws is poisoned before every launch)
  hipMemsetAsync(ws + O_XX, 0, (2*B*CQ + 16)*sizeof(float), stream);

  k1_fc  <<<B*NN,    256, 0, stream>>>(x, Wc, bc, ws);
  k1b_l2 <<<1,       128, 0, stream>>>(ws);
  k2_amax<<<B*NN,    256, 0, stream>>>(ws);
  k2b_tr <<<B*16*16, 256, 0, stream>>>(ws);
  k3_xg  <<<B*NCH,   256, 0, stream>>>(ws);
  k4_out <<<B*4,     256, 0, stream>>>(Wg, bg, ws, out);
}

// Round 2
// 259.441 us; speedup vs baseline: 1.2815x; 1.2815x over previous
//
#include <hip/hip_runtime.h>
#include <hip/hip_bf16.h>
#include <math.h>

// Problem constants
#define B    8
#define C4   64
#define CQ   16
#define NN   512
#define L4   12
#define NCH1 8            // n's per k1 block
#define KSPL 4            // K-split in pass-2 GEMM
#define KT   128          // k-tile in final kernel

// workspace layout (float offsets)
#define O_T    0                              // T[b][n][c][q]              4194304
#define O_FL   (O_T + (size_t)B*NN*C4*CQ)     // Fl[b][q][k]                  65536
#define O_XX   (O_FL + (size_t)B*CQ*NN)       // [B][CQ]                        128
#define O_YY   (O_XX + B*CQ)                  //                                128
#define O_L2   (O_YY + B*CQ)                  // [B] 1/l2 (+pad)                 16
#define O_AMAX (O_L2 + 16)                    // A[b][n][k]                 2097152
#define O_WARR (O_AMAX + (size_t)B*NN*NN)     // W[b][n][k]=A[b][k][n]      2097152
#define O_PART (O_WARR + (size_t)B*NN*NN)     // [B][KSPL][C4][NN]          1048576

// K1: Fc, Fl, norms, and T[n,c,q] = sum_j Fc[q,n,j]*x[c,n,j]
__global__ __launch_bounds__(256) void k1_fc(const float* __restrict__ x,
                                             const float* __restrict__ Wc,
                                             const float* __restrict__ bc,
                                             float* __restrict__ ws) {
  int blk = blockIdx.x;                // b*64 + nchunk
  int b = blk >> 6;
  int n0 = (blk & 63) * NCH1;
  int t = threadIdx.x;
  __shared__ __align__(16) float xs[C4*NCH1*L4];   // [c][nl][j] 6144
  __shared__ float wcs[CQ*C4];                     // [q][c]
  __shared__ float bcs[CQ];
  __shared__ __align__(16) float fcs[NCH1*CQ*L4];  // [nl][q][j] 1536

  for (int e = t; e < CQ*C4; e += 256) wcs[e] = Wc[e];
  if (t < CQ) bcs[t] = bc[t];
  // stage x for 8 n's: global [c][n][j], per c a 96-float contiguous segment
  const float* xb = x + (size_t)b*C4*NN*L4 + (size_t)n0*L4;
  {
    const float4* src0 = (const float4*)xb;
    for (int f = t; f < (C4*NCH1*L4)/4; f += 256) {
      int c = f / (NCH1*L4/4);
      int r = f - c*(NCH1*L4/4);
      float4 v = *(const float4*)(xb + (size_t)c*NN*L4 + r*4);
      *(float4*)(xs + c*(NCH1*L4) + r*4) = v;
    }
    (void)src0;
  }
  __syncthreads();
  // Fc entries: [nl][q][j], 1536 total
  for (int e = t; e < NCH1*CQ*L4; e += 256) {
    int nl = e / (CQ*L4);
    int rem = e - nl*(CQ*L4);
    int q = rem / L4, j = rem - q*L4;
    float acc = bcs[q];
    #pragma unroll
    for (int c = 0; c < C4; ++c) acc += wcs[q*C4 + c] * xs[c*(NCH1*L4) + nl*L4 + j];
    fcs[e] = acc;
    if (j == L4-1) ws[O_FL + ((size_t)b*CQ + q)*NN + n0 + nl] = acc;
  }
  __syncthreads();
  if (t < CQ) {
    float yy = 0.f, xx = 0.f;
    for (int nl = 0; nl < NCH1; ++nl) {
      #pragma unroll
      for (int j = 0; j < L4; ++j) { float v = fcs[nl*(CQ*L4) + t*L4 + j]; yy += v*v; }
      float w = fcs[nl*(CQ*L4) + t*L4 + (L4-1)];
      xx += w*w;
    }
    atomicAdd(ws + O_YY + b*CQ + t, yy);
    atomicAdd(ws + O_XX + b*CQ + t, xx);
  }
  // T: per nl, thread t computes entries (c = t>>2, q = (t&3)*4 .. +3)
  {
    int c = t >> 2, q0 = (t & 3) * 4;
    for (int nl = 0; nl < NCH1; ++nl) {
      float xr[L4];
      *(float4*)&xr[0] = *(const float4*)(xs + c*(NCH1*L4) + nl*L4);
      *(float4*)&xr[4] = *(const float4*)(xs + c*(NCH1*L4) + nl*L4 + 4);
      *(float4*)&xr[8] = *(const float4*)(xs + c*(NCH1*L4) + nl*L4 + 8);
      float4 tv; float* tvp = (float*)&tv;
      #pragma unroll
      for (int i = 0; i < 4; ++i) {
        float a = 0.f;
        #pragma unroll
        for (int j = 0; j < L4; ++j) a += fcs[nl*(CQ*L4) + (q0+i)*L4 + j] * xr[j];
        tvp[i] = a;
      }
      *(float4*)(ws + O_T + ((size_t)b*NN + n0 + nl)*(C4*CQ) + t*4) = tv;
    }
  }
}

// K1b: l2inv[b]
__global__ void k1b_l2(float* __restrict__ ws) {
  int t = threadIdx.x;              // 128 threads = B*CQ
  __shared__ float s[B*CQ];
  s[t] = sqrtf(ws[O_XX + t]) * sqrtf(ws[O_YY + t]);
  __syncthreads();
  if (t < B) {
    float sum = 0.f;
    #pragma unroll
    for (int q = 0; q < CQ; ++q) sum += s[t*CQ + q];
    ws[O_L2 + t] = 1.0f / sum;
  }
}

// K2 (pass 1): A[b][n][k] = relu(tanh(l2inv * max_c sum_q Fl[q,k]*T[n,c,q]))
// 256 threads = 2 n  x  128 threads; 4 k per thread.
__global__ __launch_bounds__(256, 4) void k2_amax(float* __restrict__ ws) {
  int blk = blockIdx.x;             // b*256 + pair
  int b = blk >> 8;
  int n0 = (blk & 255) * 2;
  int t = threadIdx.x;
  int nsub = t >> 7;
  int tloc = t & 127;
  __shared__ __align__(16) float ts[2*C4*CQ];
  {
    const float4* src = (const float4*)(ws + O_T + ((size_t)b*NN + n0)*(C4*CQ));
    float4* dst = (float4*)ts;
    dst[t] = src[t];
    dst[t+256] = src[t+256];
  }
  float l2inv = ws[O_L2 + b];
  float fl[4][CQ];
  const float* flb = ws + O_FL + (size_t)b*CQ*NN;
  #pragma unroll
  for (int q = 0; q < CQ; ++q) {
    #pragma unroll
    for (int i = 0; i < 4; ++i) fl[i][q] = flb[q*NN + tloc + 128*i];
  }
  __syncthreads();
  float m[4] = {-INFINITY, -INFINITY, -INFINITY, -INFINITY};
  const float* tsn = ts + nsub*(C4*CQ);
  for (int c = 0; c < C4; ++c) {
    float tc[CQ];
    const float4* tq = (const float4*)(tsn + c*CQ);
    *(float4*)&tc[0] = tq[0]; *(float4*)&tc[4] = tq[1];
    *(float4*)&tc[8] = tq[2]; *(float4*)&tc[12] = tq[3];
    #pragma unroll
    for (int i = 0; i < 4; ++i) {
      float d = 0.f;
      #pragma unroll
      for (int q = 0; q < CQ; ++q) d += fl[i][q] * tc[q];
      m[i] = fmaxf(m[i], d);
    }
  }
  float* am = ws + O_AMAX + ((size_t)b*NN + (n0 + nsub))*NN;
  #pragma unroll
  for (int i = 0; i < 4; ++i)
    am[tloc + 128*i] = fmaxf(tanhf(m[i]*l2inv), 0.f);
}

// K2b: W[b][n][k] = A[b][k][n]
__global__ __launch_bounds__(256) void k2b_tr(float* __restrict__ ws) {
  int blk = blockIdx.x;             // b*256 + bi*16 + bj
  int b  = blk >> 8;
  int bi = (blk >> 4) & 15;
  int bj = blk & 15;
  int t = threadIdx.x;
  int tx = t & 31, ty = t >> 5;
  __shared__ float tile[32][33];
  const float* am = ws + O_AMAX + (size_t)b*NN*NN;
  float* wa = ws + O_WARR + (size_t)b*NN*NN;
  #pragma unroll
  for (int i = 0; i < 4; ++i) {
    int row = ty + i*8;
    tile[row][tx] = am[(size_t)(bi*32+row)*NN + bj*32 + tx];
  }
  __syncthreads();
  #pragma unroll
  for (int i = 0; i < 4; ++i) {
    int row = ty + i*8;
    wa[(size_t)(bj*32+row)*NN + bi*32 + tx] = tile[tx][row];
  }
}

// K3 (pass 2): per b GEMM  U[(c,q),k] = sum_n T[n,(c,q)] * W[n,k],
// epilogue folds Fl*l2inv and reduces q -> partial xg[c,k].
// Grid: (((b*KSPL + ks)*8 + mb)*4 + nb); 256 thr = 16x16; frag 8m x 8k.
__global__ __launch_bounds__(256, 4) void k3_gemm(float* __restrict__ ws) {
  int id = blockIdx.x;
  int nb = id & 3;
  int mb = (id >> 2) & 7;
  int ks = (id >> 5) & 3;
  int b  = id >> 7;
  int t = threadIdx.x;
  int tm = t >> 4, tn = t & 15;
  __shared__ __align__(16) float a_lds[16*128];
  __shared__ __align__(16) float b_lds[16*128];
  __shared__ __align__(16) float fl_lds[16*128];
  float l2inv = ws[O_L2 + b];
  {
    const float* flb = ws + O_FL + (size_t)b*CQ*NN + nb*128;
    for (int f = t; f < 512; f += 256) {
      int q = f >> 5, col = (f & 31) * 4;
      float4 v = *(const float4*)(flb + q*NN + col);
      v.x *= l2inv; v.y *= l2inv; v.z *= l2inv; v.w *= l2inv;
      *(float4*)(fl_lds + q*128 + col) = v;
    }
  }
  float acc[8][8];
  #pragma unroll
  for (int i = 0; i < 8; ++i)
    #pragma unroll
    for (int j = 0; j < 8; ++j) acc[i][j] = 0.f;

  const float* Tb = ws + O_T + (size_t)b*NN*(C4*CQ) + mb*128;
  const float* Wb = ws + O_WARR + (size_t)b*NN*NN + nb*128;
  int row = t >> 5, colf = (t & 31) * 4;

  for (int nc = 0; nc < 8; ++nc) {
    int nbase = ks*128 + nc*16;
    __syncthreads();
    #pragma unroll
    for (int r8 = 0; r8 < 2; ++r8) {
      int rr = row + r8*8;
      *(float4*)(a_lds + rr*128 + colf) = *(const float4*)(Tb + (size_t)(nbase+rr)*(C4*CQ) + colf);
      *(float4*)(b_lds + rr*128 + colf) = *(const float4*)(Wb + (size_t)(nbase+rr)*NN + colf);
    }
    __syncthreads();
    #pragma unroll
    for (int nn = 0; nn < 16; ++nn) {
      float av[8], bv[8];
      *(float4*)&av[0] = *(const float4*)(a_lds + nn*128 + tm*8);
      *(float4*)&av[4] = *(const float4*)(a_lds + nn*128 + tm*8 + 4);
      *(float4*)&bv[0] = *(const float4*)(b_lds + nn*128 + tn*4);
      *(float4*)&bv[4] = *(const float4*)(b_lds + nn*128 + 64 + tn*4);
      #pragma unroll
      for (int i = 0; i < 8; ++i)
        #pragma unroll
        for (int j = 0; j < 8; ++j) acc[i][j] += av[i]*bv[j];
    }
  }
  // epilogue: q-reduce with Fl weights
  int qbase = (tm & 1) * 8;
  float s0[4], s1[4];
  #pragma unroll
  for (int j = 0; j < 4; ++j) { s0[j] = 0.f; s1[j] = 0.f; }
  #pragma unroll
  for (int i = 0; i < 8; ++i) {
    int q = qbase + i;
    float f0[4], f1[4];
    *(float4*)f0 = *(const float4*)(fl_lds + q*128 + tn*4);
    *(float4*)f1 = *(const float4*)(fl_lds + q*128 + 64 + tn*4);
    #pragma unroll
    for (int j = 0; j < 4; ++j) { s0[j] += f0[j]*acc[i][j]; s1[j] += f1[j]*acc[i][4+j]; }
  }
  __syncthreads();
  int u = tm >> 1;
  if (tm & 1) {
    *(float4*)(a_lds + u*128 + tn*4)      = *(float4*)s0;
    *(float4*)(a_lds + u*128 + 64 + tn*4) = *(float4*)s1;
  }
  __syncthreads();
  if (!(tm & 1)) {
    float4 p0 = *(const float4*)(a_lds + u*128 + tn*4);
    float4 p1 = *(const float4*)(a_lds + u*128 + 64 + tn*4);
    s0[0]+=p0.x; s0[1]+=p0.y; s0[2]+=p0.z; s0[3]+=p0.w;
    s1[0]+=p1.x; s1[1]+=p1.y; s1[2]+=p1.z; s1[3]+=p1.w;
    int c = mb*8 + u;
    float* outp = ws + O_PART + (((size_t)(b*KSPL + ks)*C4 + c)*NN) + nb*128;
    *(float4*)(outp + tn*4)      = *(float4*)s0;
    *(float4*)(outp + 64 + tn*4) = *(float4*)s1;
  }
}

// K4: reduce KSPL partials -> xg, then Fg = W_gcn xg + b_gcn
__global__ __launch_bounds__(256) void k4_out(const float* __restrict__ Wg,
                                              const float* __restrict__ bg,
                                              const float* __restrict__ ws,
                                              float* __restrict__ out) {
  int blk = blockIdx.x;             // b*4 + kc
  int b = blk >> 2, kc = blk & 3;
  int t = threadIdx.x;
  __shared__ float xg[C4][KT+1];
  __shared__ float wg[C4*C4];
  for (int e = t; e < C4*C4; e += 256) wg[e] = Wg[e];
  for (int e = t; e < C4*KT; e += 256) {
    int c = e >> 7, kk = e & (KT-1);
    float s = 0.f;
    #pragma unroll
    for (int chn = 0; chn < KSPL; ++chn)
      s += ws[O_PART + (((size_t)(b*KSPL + chn)*C4 + c)*NN) + kc*KT + kk];
    xg[c][kk] = s;
  }
  __syncthreads();
  int kk = t & (KT-1);
  int ohalf = t >> 7;
  for (int oi = 0; oi < 32; ++oi) {
    int o = ohalf*32 + oi;
    float acc = bg[o];
    #pragma unroll
    for (int c = 0; c < C4; ++c) acc += wg[o*C4 + c] * xg[c][kk];
    out[((size_t)(b*C4 + o))*NN + kc*KT + kk] = acc;
  }
}

extern "C" void kernel_launch(void* const* d_in, const int* in_sizes, int n_in,
                              void* d_out, int out_size, void* d_ws, size_t ws_size,
                              hipStream_t stream) {
  const float* x  = (const float*)d_in[0];
  const float* Wc = (const float*)d_in[1];
  const float* bc = (const float*)d_in[2];
  const float* Wg = (const float*)d_in[3];
  const float* bg = (const float*)d_in[4];
  float* ws  = (float*)d_ws;
  float* out = (float*)d_out;

  hipMemsetAsync(ws + O_XX, 0, (2*B*CQ + 16)*sizeof(float), stream);

  k1_fc  <<<B*64,        256, 0, stream>>>(x, Wc, bc, ws);
  k1b_l2 <<<1,           128, 0, stream>>>(ws);
  k2_amax<<<B*256,       256, 0, stream>>>(ws);
  k2b_tr <<<B*16*16,     256, 0, stream>>>(ws);
  k3_gemm<<<B*KSPL*8*4,  256, 0, stream>>>(ws);
  k4_out <<<B*4,         256, 0, stream>>>(Wg, bg, ws, out);
}

// Round 3
// 249.068 us; speedup vs baseline: 1.3348x; 1.0416x over previous
//
#include <hip/hip_runtime.h>
#include <hip/hip_bf16.h>
#include <math.h>

// Problem constants
#define B    8
#define C4   64
#define CQ   16
#define NN   512
#define L4   12
#define NCH1 8            // n's per k1 block
#define KSPL 4            // K-split in pass-2 GEMM
#define KT   128          // k-tile in final kernel

// workspace layout (float offsets)
#define O_T    0                              // T[b][n][c][q]              4194304
#define O_FL   (O_T + (size_t)B*NN*C4*CQ)     // Fl[b][q][k]                  65536
#define O_XX   (O_FL + (size_t)B*CQ*NN)       // [B][CQ]                        128
#define O_YY   (O_XX + B*CQ)                  //                                128
#define O_L2   (O_YY + B*CQ)                  // [B] 1/l2 (+pad)                 16
#define O_AMAX (O_L2 + 16)                    // A[b][n][k]                 2097152
#define O_WARR (O_AMAX + (size_t)B*NN*NN)     // W[b][n][k]=A[b][k][n]      2097152
#define O_PART (O_WARR + (size_t)B*NN*NN)     // [B][KSPL][C4][NN]          1048576

// K1: Fc, Fl, norms, and T[n,c,q] = sum_j Fc[q,n,j]*x[c,n,j]
__global__ __launch_bounds__(256) void k1_fc(const float* __restrict__ x,
                                             const float* __restrict__ Wc,
                                             const float* __restrict__ bc,
                                             float* __restrict__ ws) {
  int blk = blockIdx.x;                // b*64 + nchunk
  int b = blk >> 6;
  int n0 = (blk & 63) * NCH1;
  int t = threadIdx.x;
  __shared__ __align__(16) float xs[C4*NCH1*L4];   // [c][nl][j] 6144
  __shared__ float wcs[CQ*C4];                     // [q][c]
  __shared__ float bcs[CQ];
  __shared__ __align__(16) float fcs[NCH1*CQ*L4];  // [nl][q][j] 1536

  for (int e = t; e < CQ*C4; e += 256) wcs[e] = Wc[e];
  if (t < CQ) bcs[t] = bc[t];
  // stage x for 8 n's: global [c][n][j], per c a 96-float contiguous segment
  const float* xb = x + (size_t)b*C4*NN*L4 + (size_t)n0*L4;
  for (int f = t; f < (C4*NCH1*L4)/4; f += 256) {
    int c = f / (NCH1*L4/4);
    int r = f - c*(NCH1*L4/4);
    float4 v = *(const float4*)(xb + (size_t)c*NN*L4 + r*4);
    *(float4*)(xs + c*(NCH1*L4) + r*4) = v;
  }
  __syncthreads();
  // Fc entries: [nl][q][j], 1536 total
  for (int e = t; e < NCH1*CQ*L4; e += 256) {
    int nl = e / (CQ*L4);
    int rem = e - nl*(CQ*L4);
    int q = rem / L4, j = rem - q*L4;
    float acc = bcs[q];
    #pragma unroll
    for (int c = 0; c < C4; ++c) acc += wcs[q*C4 + c] * xs[c*(NCH1*L4) + nl*L4 + j];
    fcs[e] = acc;
    if (j == L4-1) ws[O_FL + ((size_t)b*CQ + q)*NN + n0 + nl] = acc;
  }
  __syncthreads();
  if (t < CQ) {
    float yy = 0.f, xx = 0.f;
    for (int nl = 0; nl < NCH1; ++nl) {
      #pragma unroll
      for (int j = 0; j < L4; ++j) { float v = fcs[nl*(CQ*L4) + t*L4 + j]; yy += v*v; }
      float w = fcs[nl*(CQ*L4) + t*L4 + (L4-1)];
      xx += w*w;
    }
    atomicAdd(ws + O_YY + b*CQ + t, yy);
    atomicAdd(ws + O_XX + b*CQ + t, xx);
  }
  // T: per nl, thread t computes entries (c = t>>2, q = (t&3)*4 .. +3)
  {
    int c = t >> 2, q0 = (t & 3) * 4;
    for (int nl = 0; nl < NCH1; ++nl) {
      float xr[L4];
      *(float4*)&xr[0] = *(const float4*)(xs + c*(NCH1*L4) + nl*L4);
      *(float4*)&xr[4] = *(const float4*)(xs + c*(NCH1*L4) + nl*L4 + 4);
      *(float4*)&xr[8] = *(const float4*)(xs + c*(NCH1*L4) + nl*L4 + 8);
      float4 tv; float* tvp = (float*)&tv;
      #pragma unroll
      for (int i = 0; i < 4; ++i) {
        float a = 0.f;
        #pragma unroll
        for (int j = 0; j < L4; ++j) a += fcs[nl*(CQ*L4) + (q0+i)*L4 + j] * xr[j];
        tvp[i] = a;
      }
      *(float4*)(ws + O_T + ((size_t)b*NN + n0 + nl)*(C4*CQ) + t*4) = tv;
    }
  }
}

// K1b: l2inv[b]
__global__ void k1b_l2(float* __restrict__ ws) {
  int t = threadIdx.x;              // 128 threads = B*CQ
  __shared__ float s[B*CQ];
  s[t] = sqrtf(ws[O_XX + t]) * sqrtf(ws[O_YY + t]);
  __syncthreads();
  if (t < B) {
    float sum = 0.f;
    #pragma unroll
    for (int q = 0; q < CQ; ++q) sum += s[t*CQ + q];
    ws[O_L2 + t] = 1.0f / sum;
  }
}

// K2 (pass 1): A[b][n][k] = relu(tanh(l2inv * max_c sum_q Fl[q,k]*T[n,c,q]))
// One n per block; 256 threads x 2 k each. fl = 32 VGPRs -> no spill.
__global__ __launch_bounds__(256, 4) void k2_amax(float* __restrict__ ws) {
  int blk = blockIdx.x;             // b*512 + n
  int b = blk >> 9;
  int t = threadIdx.x;
  __shared__ __align__(16) float ts[C4*CQ];
  {
    const float4* src = (const float4*)(ws + O_T + (size_t)blk*(C4*CQ));
    ((float4*)ts)[t] = src[t];
  }
  float l2inv = ws[O_L2 + b];
  float fl0[CQ], fl1[CQ];
  const float* flb = ws + O_FL + (size_t)b*CQ*NN;
  #pragma unroll
  for (int q = 0; q < CQ; ++q) {
    fl0[q] = flb[q*NN + t];
    fl1[q] = flb[q*NN + t + 256];
  }
  __syncthreads();
  float m0 = -INFINITY, m1 = -INFINITY;
  for (int c = 0; c < C4; ++c) {
    float tc[CQ];
    const float4* tq = (const float4*)(ts + c*CQ);
    *(float4*)&tc[0] = tq[0]; *(float4*)&tc[4] = tq[1];
    *(float4*)&tc[8] = tq[2]; *(float4*)&tc[12] = tq[3];
    float d0 = 0.f, d1 = 0.f;
    #pragma unroll
    for (int q = 0; q < CQ; ++q) { d0 += fl0[q]*tc[q]; d1 += fl1[q]*tc[q]; }
    m0 = fmaxf(m0, d0); m1 = fmaxf(m1, d1);
  }
  float* am = ws + O_AMAX + (size_t)blk*NN;
  am[t]     = fmaxf(tanhf(m0*l2inv), 0.f);
  am[t+256] = fmaxf(tanhf(m1*l2inv), 0.f);
}

// K2b: W[b][n][k] = A[b][k][n]
__global__ __launch_bounds__(256) void k2b_tr(float* __restrict__ ws) {
  int blk = blockIdx.x;             // b*256 + bi*16 + bj
  int b  = blk >> 8;
  int bi = (blk >> 4) & 15;
  int bj = blk & 15;
  int t = threadIdx.x;
  int tx = t & 31, ty = t >> 5;
  __shared__ float tile[32][33];
  const float* am = ws + O_AMAX + (size_t)b*NN*NN;
  float* wa = ws + O_WARR + (size_t)b*NN*NN;
  #pragma unroll
  for (int i = 0; i < 4; ++i) {
    int row = ty + i*8;
    tile[row][tx] = am[(size_t)(bi*32+row)*NN + bj*32 + tx];
  }
  __syncthreads();
  #pragma unroll
  for (int i = 0; i < 4; ++i) {
    int row = ty + i*8;
    wa[(size_t)(bj*32+row)*NN + bi*32 + tx] = tile[tx][row];
  }
}

// K3 (pass 2): per b GEMM  U[(c,q),k] = sum_n T[n,(c,q)] * W[n,k],
// epilogue folds Fl*l2inv and reduces q -> partial xg[c,k].
// Grid: (((b*KSPL + ks)*8 + mb)*4 + nb); 256 thr = 16x16; frag 8m x 8k.
__global__ __launch_bounds__(256, 4) void k3_gemm(float* __restrict__ ws) {
  int id = blockIdx.x;
  int nb = id & 3;
  int mb = (id >> 2) & 7;
  int ks = (id >> 5) & 3;
  int b  = id >> 7;
  int t = threadIdx.x;
  int tm = t >> 4, tn = t & 15;
  __shared__ __align__(16) float a_lds[16*128];
  __shared__ __align__(16) float b_lds[16*128];
  __shared__ __align__(16) float fl_lds[16*128];
  float l2inv = ws[O_L2 + b];
  {
    const float* flb = ws + O_FL + (size_t)b*CQ*NN + nb*128;
    for (int f = t; f < 512; f += 256) {
      int q = f >> 5, col = (f & 31) * 4;
      float4 v = *(const float4*)(flb + q*NN + col);
      v.x *= l2inv; v.y *= l2inv; v.z *= l2inv; v.w *= l2inv;
      *(float4*)(fl_lds + q*128 + col) = v;
    }
  }
  float acc[8][8];
  #pragma unroll
  for (int i = 0; i < 8; ++i)
    #pragma unroll
    for (int j = 0; j < 8; ++j) acc[i][j] = 0.f;

  const float* Tb = ws + O_T + (size_t)b*NN*(C4*CQ) + mb*128;
  const float* Wb = ws + O_WARR + (size_t)b*NN*NN + nb*128;
  int row = t >> 5, colf = (t & 31) * 4;

  for (int nc = 0; nc < 8; ++nc) {
    int nbase = ks*128 + nc*16;
    __syncthreads();
    #pragma unroll
    for (int r8 = 0; r8 < 2; ++r8) {
      int rr = row + r8*8;
      *(float4*)(a_lds + rr*128 + colf) = *(const float4*)(Tb + (size_t)(nbase+rr)*(C4*CQ) + colf);
      *(float4*)(b_lds + rr*128 + colf) = *(const float4*)(Wb + (size_t)(nbase+rr)*NN + colf);
    }
    __syncthreads();
    #pragma unroll
    for (int nn = 0; nn < 16; ++nn) {
      float av[8], bv[8];
      *(float4*)&av[0] = *(const float4*)(a_lds + nn*128 + tm*8);
      *(float4*)&av[4] = *(const float4*)(a_lds + nn*128 + tm*8 + 4);
      *(float4*)&bv[0] = *(const float4*)(b_lds + nn*128 + tn*4);
      *(float4*)&bv[4] = *(const float4*)(b_lds + nn*128 + 64 + tn*4);
      #pragma unroll
      for (int i = 0; i < 8; ++i)
        #pragma unroll
        for (int j = 0; j < 8; ++j) acc[i][j] += av[i]*bv[j];
    }
  }
  // epilogue: q-reduce with Fl weights
  int qbase = (tm & 1) * 8;
  float s0[4], s1[4];
  #pragma unroll
  for (int j = 0; j < 4; ++j) { s0[j] = 0.f; s1[j] = 0.f; }
  #pragma unroll
  for (int i = 0; i < 8; ++i) {
    int q = qbase + i;
    float f0[4], f1[4];
    *(float4*)f0 = *(const float4*)(fl_lds + q*128 + tn*4);
    *(float4*)f1 = *(const float4*)(fl_lds + q*128 + 64 + tn*4);
    #pragma unroll
    for (int j = 0; j < 4; ++j) { s0[j] += f0[j]*acc[i][j]; s1[j] += f1[j]*acc[i][4+j]; }
  }
  __syncthreads();
  int u = tm >> 1;
  if (tm & 1) {
    *(float4*)(a_lds + u*128 + tn*4)      = *(float4*)s0;
    *(float4*)(a_lds + u*128 + 64 + tn*4) = *(float4*)s1;
  }
  __syncthreads();
  if (!(tm & 1)) {
    float4 p0 = *(const float4*)(a_lds + u*128 + tn*4);
    float4 p1 = *(const float4*)(a_lds + u*128 + 64 + tn*4);
    s0[0]+=p0.x; s0[1]+=p0.y; s0[2]+=p0.z; s0[3]+=p0.w;
    s1[0]+=p1.x; s1[1]+=p1.y; s1[2]+=p1.z; s1[3]+=p1.w;
    int c = mb*8 + u;
    float* outp = ws + O_PART + (((size_t)(b*KSPL + ks)*C4 + c)*NN) + nb*128;
    *(float4*)(outp + tn*4)      = *(float4*)s0;
    *(float4*)(outp + 64 + tn*4) = *(float4*)s1;
  }
}

// K4: reduce KSPL partials -> xg, then Fg = W_gcn xg + b_gcn
__global__ __launch_bounds__(256) void k4_out(const float* __restrict__ Wg,
                                              const float* __restrict__ bg,
                                              const float* __restrict__ ws,
                                              float* __restrict__ out) {
  int blk = blockIdx.x;             // b*4 + kc
  int b = blk >> 2, kc = blk & 3;
  int t = threadIdx.x;
  __shared__ float xg[C4][KT+1];
  __shared__ float wg[C4*C4];
  for (int e = t; e < C4*C4; e += 256) wg[e] = Wg[e];
  for (int e = t; e < C4*KT; e += 256) {
    int c = e >> 7, kk = e & (KT-1);
    float s = 0.f;
    #pragma unroll
    for (int chn = 0; chn < KSPL; ++chn)
      s += ws[O_PART + (((size_t)(b*KSPL + chn)*C4 + c)*NN) + kc*KT + kk];
    xg[c][kk] = s;
  }
  __syncthreads();
  int kk = t & (KT-1);
  int ohalf = t >> 7;
  for (int oi = 0; oi < 32; ++oi) {
    int o = ohalf*32 + oi;
    float acc = bg[o];
    #pragma unroll
    for (int c = 0; c < C4; ++c) acc += wg[o*C4 + c] * xg[c][kk];
    out[((size_t)(b*C4 + o))*NN + kc*KT + kk] = acc;
  }
}

extern "C" void kernel_launch(void* const* d_in, const int* in_sizes, int n_in,
                              void* d_out, int out_size, void* d_ws, size_t ws_size,
                              hipStream_t stream) {
  const float* x  = (const float*)d_in[0];
  const float* Wc = (const float*)d_in[1];
  const float* bc = (const float*)d_in[2];
  const float* Wg = (const float*)d_in[3];
  const float* bg = (const float*)d_in[4];
  float* ws  = (float*)d_ws;
  float* out = (float*)d_out;

  hipMemsetAsync(ws + O_XX, 0, (2*B*CQ + 16)*sizeof(float), stream);

  k1_fc  <<<B*64,        256, 0, stream>>>(x, Wc, bc, ws);
  k1b_l2 <<<1,           128, 0, stream>>>(ws);
  k2_amax<<<B*NN,        256, 0, stream>>>(ws);
  k2b_tr <<<B*16*16,     256, 0, stream>>>(ws);
  k3_gemm<<<B*KSPL*8*4,  256, 0, stream>>>(ws);
  k4_out <<<B*4,         256, 0, stream>>>(Wg, bg, ws, out);
}